// Round 7
// baseline (695.917 us; speedup 1.0000x reference)
//
#include <hip/hip_runtime.h>

typedef _Float16 half8 __attribute__((ext_vector_type(8)));
typedef float floatx4 __attribute__((ext_vector_type(4)));

#define NSTEPS 512
#define IN_F   23
#define HSTRIDE 72   // LDS row stride in fp16 elements (64 + 8 pad), 16B-aligned rows

#define LOG2E      1.4426950408889634f
#define NEG2LOG2E -2.8853900817779268f

#if __has_builtin(__builtin_amdgcn_exp2f)
#define EXP2(x) __builtin_amdgcn_exp2f(x)
#else
#define EXP2(x) exp2f(x)
#endif

__device__ __forceinline__ float fast_rcp(float x) { return __builtin_amdgcn_rcpf(x); }

// split-precision accumulate with exact weights, f16-hi activations:
// acc += Ah * (Bhi + Blo)
#define MFMA2(acc, Ah, Bhi, Blo)                                                   \
    acc = __builtin_amdgcn_mfma_f32_16x16x32_f16((Ah), (Bhi), (acc), 0, 0, 0);     \
    acc = __builtin_amdgcn_mfma_f32_16x16x32_f16((Ah), (Blo), (acc), 0, 0, 0);

// Anti-phase software pipeline, 2 barriers/step:
//   half1: grp0 MFMA(i)            | grp1 ACT(i-2) + write h1(i-2)
//   barA
//   half2: grp0 ACT(i)+write h0(i) | grp1 frag reads + MFMA(i-1)
//   barB
// At any instant one wave-group is on the matrix pipe and the other on the
// VALU/trans pipes -> pipes overlap instead of alternating (round-6 counters
// showed MFMA 38% + VALU 55% ~= 93% serialized).
// Numerics identical to round-6 kernel (same ops, same order per step).
__global__ __launch_bounds__(512, 1)
void lstm2_fused(const float* __restrict__ x,
                 const float* __restrict__ Wih0, const float* __restrict__ Whh0,
                 const float* __restrict__ bih0, const float* __restrict__ bhh0,
                 const float* __restrict__ Wih1, const float* __restrict__ Whh1,
                 const float* __restrict__ bih1, const float* __restrict__ bhh1,
                 const float* __restrict__ fcw, const float* __restrict__ fcb,
                 float* __restrict__ out)
{
    __shared__ _Float16 h0buf[2][16 * HSTRIDE];   // double-buffered h0
    __shared__ _Float16 h1buf[16 * HSTRIDE];      // single-buffered h1 (grp1-only)
    __shared__ float red[4][16];

    const int tid  = threadIdx.x;
    const int w8   = tid >> 6;        // 0..7
    const int grp  = w8 >> 2;         // 0: layer0, 1: layer1
    const int wg   = w8 & 3;          // wave-in-group -> hidden units [16wg,16wg+16)
    const int lane = tid & 63;
    const int l15  = lane & 15;       // A row (batch) / B col / C col (hidden)
    const int krow = lane >> 4;       // k-group 0..3
    const int b0   = blockIdx.x * 8;

    // ---- zero LDS h buffers (h0[-1]=0, h1[-1]=0) ----
    {
        _Float16* z = &h0buf[0][0];
        for (int idx = tid; idx < 3 * 16 * HSTRIDE; idx += 512)
            z[idx] = (_Float16)0.f;   // h0buf[0], h0buf[1], h1buf are contiguous
    }

    // ---- weights (hi/lo split, gate-scaled), register-unified across groups ----
    half8 wi_h[4][2], wi_l[4][2], wh_h[4][2], wh_l[4][2];
    float bias[4];
    {
        const float* WI = grp ? Wih1 : Wih0;
        const float* WH = grp ? Whh1 : Whh0;
        const float* BI = grp ? bih1 : bih0;
        const float* BH = grp ? bhh1 : bhh0;
        const float gs[4] = {LOG2E, LOG2E, 2.f * LOG2E, LOG2E};
        #pragma unroll
        for (int q = 0; q < 4; ++q) {
            const int g = q * 64 + wg * 16 + l15;   // gate row
            if (!grp) {
                #pragma unroll
                for (int j = 0; j < 8; ++j) {
                    const int k = krow * 8 + j;
                    const float v = ((k < IN_F) ? WI[g * IN_F + k] : 0.f) * gs[q];
                    const _Float16 hi = (_Float16)v;
                    wi_h[q][0][j] = hi;
                    wi_l[q][0][j] = (_Float16)(v - (float)hi);
                    wi_h[q][1][j] = (_Float16)0.f;
                    wi_l[q][1][j] = (_Float16)0.f;
                }
            } else {
                #pragma unroll
                for (int kk = 0; kk < 2; ++kk) {
                    #pragma unroll
                    for (int j = 0; j < 8; ++j) {
                        const int k = kk * 32 + krow * 8 + j;
                        const float v = WI[g * 64 + k] * gs[q];
                        const _Float16 hi = (_Float16)v;
                        wi_h[q][kk][j] = hi;
                        wi_l[q][kk][j] = (_Float16)(v - (float)hi);
                    }
                }
            }
            #pragma unroll
            for (int kk = 0; kk < 2; ++kk) {
                #pragma unroll
                for (int j = 0; j < 8; ++j) {
                    const int k = kk * 32 + krow * 8 + j;
                    const float v = WH[g * 64 + k] * gs[q];
                    const _Float16 hi = (_Float16)v;
                    wh_h[q][kk][j] = hi;
                    wh_l[q][kk][j] = (_Float16)(v - (float)hi);
                }
            }
            bias[q] = (BI[g] + BH[g]) * gs[q];
        }
    }
    const float fcwv = fcw[wg * 16 + l15];

    // ---- state ----
    floatx4 c = {0.f, 0.f, 0.f, 0.f};
    half8 in0h, in1h;                 // input operand (grp0: x; grp1: h0)
    half8 hr0h, hr1h;                 // recurrent operand (grp0: h0; grp1: h1)
    #pragma unroll
    for (int j = 0; j < 8; ++j) {
        in0h[j] = (_Float16)0.f; in1h[j] = (_Float16)0.f;
        hr0h[j] = (_Float16)0.f; hr1h[j] = (_Float16)0.f;
    }
    floatx4 acc[4];
    #pragma unroll
    for (int q = 0; q < 4; ++q) acc[q] = (floatx4){0.f, 0.f, 0.f, 0.f};

    // x stream (grp0 only): A row l15 -> batch b0 + (l15 & 7)
    const float* xrow = x + (size_t)(b0 + (l15 & 7)) * (NSTEPS * IN_F);
    float xf[8], xfn[8];
    if (!grp) {
        #pragma unroll
        for (int j = 0; j < 8; ++j) {
            const int k = krow * 8 + j;
            xf[j] = (k < IN_F) ? xrow[k] : 0.f;   // t = 0
        }
    }

    float hv[4] = {0.f, 0.f, 0.f, 0.f};

    __syncthreads();   // LDS zero-init visible to all

    for (int i = 0; i <= NSTEPS + 1; ++i) {
        // ================= half 1 =================
        if (!grp) {
            if (i < NSTEPS) {
                // read h0(i-1) A-frags (cross-wave writes from half2(i-1), 1 barrier ago)
                const _Float16* sh = &h0buf[(i + 1) & 1][0];
                hr0h = *(const half8*)&sh[l15 * HSTRIDE + krow * 8];
                hr1h = *(const half8*)&sh[l15 * HSTRIDE + 32 + krow * 8];
                // cast x(i) to f16 fragment
                #pragma unroll
                for (int j = 0; j < 8; ++j) in0h[j] = (_Float16)xf[j];
                // MFMA step i (24 MFMAs)
                __builtin_amdgcn_s_setprio(1);
                #pragma unroll
                for (int q = 0; q < 4; ++q) {
                    floatx4 a = {bias[q], bias[q], bias[q], bias[q]};
                    MFMA2(a, in0h, wi_h[q][0], wi_l[q][0]);
                    MFMA2(a, hr0h, wh_h[q][0], wh_l[q][0]);
                    MFMA2(a, hr1h, wh_h[q][1], wh_l[q][1]);
                    acc[q] = a;
                }
                __builtin_amdgcn_s_setprio(0);
                // prefetch x(i+1)
                const int tn = (i + 1 < NSTEPS) ? (i + 1) : i;
                #pragma unroll
                for (int j = 0; j < 8; ++j) {
                    const int k = krow * 8 + j;
                    xfn[j] = (k < IN_F) ? xrow[(size_t)tn * IN_F + k] : 0.f;
                }
            }
        } else {
            if (i >= 2) {
                // ACT(i-2) from acc (computed half2(i-1)); write h1(i-2)
                #pragma unroll
                for (int r = 0; r < 4; ++r) {
                    const float iv = fast_rcp(1.f + EXP2(-acc[0][r]));
                    const float fv = fast_rcp(1.f + EXP2(-acc[1][r]));
                    const float gv = 2.f * fast_rcp(1.f + EXP2(-acc[2][r])) - 1.f;
                    const float ov = fast_rcp(1.f + EXP2(-acc[3][r]));
                    const float cn = fv * c[r] + iv * gv;
                    c[r] = cn;
                    hv[r] = ov * (2.f * fast_rcp(1.f + EXP2(NEG2LOG2E * cn)) - 1.f);
                }
                #pragma unroll
                for (int r = 0; r < 4; ++r) {
                    const int idx = (krow * 4 + r) * HSTRIDE + wg * 16 + l15;
                    h1buf[idx] = (_Float16)hv[r];
                }
            }
        }

        __syncthreads();   // bar A

        // ================= half 2 =================
        if (!grp) {
            if (i < NSTEPS) {
                // ACT(i); write h0(i)
                float h0v[4];
                #pragma unroll
                for (int r = 0; r < 4; ++r) {
                    const float iv = fast_rcp(1.f + EXP2(-acc[0][r]));
                    const float fv = fast_rcp(1.f + EXP2(-acc[1][r]));
                    const float gv = 2.f * fast_rcp(1.f + EXP2(-acc[2][r])) - 1.f;
                    const float ov = fast_rcp(1.f + EXP2(-acc[3][r]));
                    const float cn = fv * c[r] + iv * gv;
                    c[r] = cn;
                    h0v[r] = ov * (2.f * fast_rcp(1.f + EXP2(NEG2LOG2E * cn)) - 1.f);
                }
                _Float16* dst = &h0buf[i & 1][0];
                #pragma unroll
                for (int r = 0; r < 4; ++r) {
                    const int idx = (krow * 4 + r) * HSTRIDE + wg * 16 + l15;
                    dst[idx] = (_Float16)h0v[r];
                }
                #pragma unroll
                for (int j = 0; j < 8; ++j) xf[j] = xfn[j];
            }
        } else {
            if (i >= 1 && i <= NSTEPS) {
                // frag reads: h0(i-1) [written half2(i-1)] and h1(i-2) [written half1(i)]
                const _Float16* sh0 = &h0buf[(i + 1) & 1][0];
                in0h = *(const half8*)&sh0[l15 * HSTRIDE + krow * 8];
                in1h = *(const half8*)&sh0[l15 * HSTRIDE + 32 + krow * 8];
                hr0h = *(const half8*)&h1buf[l15 * HSTRIDE + krow * 8];
                hr1h = *(const half8*)&h1buf[l15 * HSTRIDE + 32 + krow * 8];
                // MFMA step i-1 (32 MFMAs)
                __builtin_amdgcn_s_setprio(1);
                #pragma unroll
                for (int q = 0; q < 4; ++q) {
                    floatx4 a = {bias[q], bias[q], bias[q], bias[q]};
                    MFMA2(a, in0h, wi_h[q][0], wi_l[q][0]);
                    MFMA2(a, in1h, wi_h[q][1], wi_l[q][1]);
                    MFMA2(a, hr0h, wh_h[q][0], wh_l[q][0]);
                    MFMA2(a, hr1h, wh_h[q][1], wh_l[q][1]);
                    acc[q] = a;
                }
                __builtin_amdgcn_s_setprio(0);
            }
        }

        __syncthreads();   // bar B
    }

    // ---- FC on last h1 (grp1 hv = h1(NSTEPS-1) from its final ACT) ----
    if (grp) {
        float p[4];
        #pragma unroll
        for (int r = 0; r < 4; ++r) p[r] = hv[r] * fcwv;
        #pragma unroll
        for (int off = 1; off < 16; off <<= 1) {
            #pragma unroll
            for (int r = 0; r < 4; ++r)
                p[r] += __shfl_xor(p[r], off, 64);
        }
        if (l15 == 0) {
            #pragma unroll
            for (int r = 0; r < 4; ++r)
                red[wg][krow * 4 + r] = p[r];
        }
    }
    __syncthreads();
    if (tid < 8) {
        float v = fcb[0];
        v += red[0][tid] + red[1][tid] + red[2][tid] + red[3][tid];
        out[b0 + tid] = v;
    }
}

extern "C" void kernel_launch(void* const* d_in, const int* in_sizes, int n_in,
                              void* d_out, int out_size, void* d_ws, size_t ws_size,
                              hipStream_t stream) {
    (void)n_in; (void)d_ws; (void)ws_size; (void)out_size;
    const float* xp    = (const float*)d_in[0];
    const float* Wih0  = (const float*)d_in[1];
    const float* Whh0  = (const float*)d_in[2];
    const float* bih0  = (const float*)d_in[3];
    const float* bhh0  = (const float*)d_in[4];
    const float* Wih1  = (const float*)d_in[5];
    const float* Whh1  = (const float*)d_in[6];
    const float* bih1  = (const float*)d_in[7];
    const float* bhh1  = (const float*)d_in[8];
    const float* fcw   = (const float*)d_in[9];
    const float* fcb   = (const float*)d_in[10];
    float* outp        = (float*)d_out;

    const int B = in_sizes[0] / (NSTEPS * IN_F);   // 2048
    const int nblocks = B / 8;                     // 256
    hipLaunchKernelGGL(lstm2_fused, dim3(nblocks), dim3(512), 0, stream,
                       xp, Wih0, Whh0, bih0, bhh0, Wih1, Whh1, bih1, bhh1,
                       fcw, fcb, outp);
}

// Round 8
// 685.847 us; speedup vs baseline: 1.0147x; 1.0147x over previous
//
#include <hip/hip_runtime.h>

typedef _Float16 half8 __attribute__((ext_vector_type(8)));
typedef float floatx4 __attribute__((ext_vector_type(4)));

#define NSTEPS 512
#define IN_F   23
#define HSTRIDE 72   // LDS row stride in fp16 elements (64 + 8 pad), 16B-aligned rows

#define LOG2E      1.4426950408889634f
#define NEG2LOG2E -2.8853900817779268f

#if __has_builtin(__builtin_amdgcn_exp2f)
#define EXP2(x) __builtin_amdgcn_exp2f(x)
#else
#define EXP2(x) exp2f(x)
#endif

__device__ __forceinline__ float fast_rcp(float x) { return __builtin_amdgcn_rcpf(x); }

// Raw block barrier with LDS-only drain: unlike __syncthreads(), does NOT
// emit s_waitcnt vmcnt(0) -- so global-memory prefetch loads stay in flight
// across the barrier (the round-7 counters showed the implicit vmcnt(0)
// drain exposing ~full HBM latency every iteration). lgkmcnt(0) guarantees
// our ds_writes are visible to other waves after s_barrier; the "memory"
// clobber keeps LDS ops from migrating across.
__device__ __forceinline__ void block_sync_lds() {
    asm volatile("s_waitcnt lgkmcnt(0)\n\ts_barrier" ::: "memory");
}

// split-precision accumulate with exact weights, f16-hi activations:
// acc += Ah * (Bhi + Blo)
#define MFMA2(acc, Ah, Bhi, Blo)                                                   \
    acc = __builtin_amdgcn_mfma_f32_16x16x32_f16((Ah), (Bhi), (acc), 0, 0, 0);     \
    acc = __builtin_amdgcn_mfma_f32_16x16x32_f16((Ah), (Blo), (acc), 0, 0, 0);

// Anti-phase software pipeline, 2 raw barriers/step:
//   half1: grp0 MFMA(i)            | grp1 h0-frag reads + ACT(i-2) + write h1(i-2)
//   barA
//   half2: grp0 ACT(i)+write h0(i) | grp1 h1-frag reads + MFMA(i-1)
//   barB
// MFMA loops are two-pass (input operands first, recurrent second) so the
// ds_read latency of recurrent fragments hides under the first MFMA pass.
__global__ __launch_bounds__(512, 1)
void lstm2_fused(const float* __restrict__ x,
                 const float* __restrict__ Wih0, const float* __restrict__ Whh0,
                 const float* __restrict__ bih0, const float* __restrict__ bhh0,
                 const float* __restrict__ Wih1, const float* __restrict__ Whh1,
                 const float* __restrict__ bih1, const float* __restrict__ bhh1,
                 const float* __restrict__ fcw, const float* __restrict__ fcb,
                 float* __restrict__ out)
{
    __shared__ _Float16 h0buf[2][16 * HSTRIDE];   // double-buffered h0
    __shared__ _Float16 h1buf[16 * HSTRIDE];      // single-buffered h1 (grp1-only)
    __shared__ float red[4][16];

    const int tid  = threadIdx.x;
    const int w8   = tid >> 6;        // 0..7
    const int grp  = w8 >> 2;         // 0: layer0, 1: layer1
    const int wg   = w8 & 3;          // wave-in-group -> hidden units [16wg,16wg+16)
    const int lane = tid & 63;
    const int l15  = lane & 15;       // A row (batch) / B col / C col (hidden)
    const int krow = lane >> 4;       // k-group 0..3
    const int b0   = blockIdx.x * 8;

    // ---- zero LDS h buffers (h0[-1]=0, h1[-1]=0) ----
    for (int idx = tid; idx < 2 * 16 * HSTRIDE; idx += 512) h0buf[0][idx] = (_Float16)0.f;
    for (int idx = tid; idx < 16 * HSTRIDE; idx += 512)     h1buf[idx]    = (_Float16)0.f;

    // ---- weights (hi/lo split, gate-scaled), register-unified across groups ----
    half8 wi_h[4][2], wi_l[4][2], wh_h[4][2], wh_l[4][2];
    float bias[4];
    {
        const float* WI = grp ? Wih1 : Wih0;
        const float* WH = grp ? Whh1 : Whh0;
        const float* BI = grp ? bih1 : bih0;
        const float* BH = grp ? bhh1 : bhh0;
        const float gs[4] = {LOG2E, LOG2E, 2.f * LOG2E, LOG2E};
        #pragma unroll
        for (int q = 0; q < 4; ++q) {
            const int g = q * 64 + wg * 16 + l15;   // gate row
            if (!grp) {
                #pragma unroll
                for (int j = 0; j < 8; ++j) {
                    const int k = krow * 8 + j;
                    const float v = ((k < IN_F) ? WI[g * IN_F + k] : 0.f) * gs[q];
                    const _Float16 hi = (_Float16)v;
                    wi_h[q][0][j] = hi;
                    wi_l[q][0][j] = (_Float16)(v - (float)hi);
                    wi_h[q][1][j] = (_Float16)0.f;
                    wi_l[q][1][j] = (_Float16)0.f;
                }
            } else {
                #pragma unroll
                for (int kk = 0; kk < 2; ++kk) {
                    #pragma unroll
                    for (int j = 0; j < 8; ++j) {
                        const int k = kk * 32 + krow * 8 + j;
                        const float v = WI[g * 64 + k] * gs[q];
                        const _Float16 hi = (_Float16)v;
                        wi_h[q][kk][j] = hi;
                        wi_l[q][kk][j] = (_Float16)(v - (float)hi);
                    }
                }
            }
            #pragma unroll
            for (int kk = 0; kk < 2; ++kk) {
                #pragma unroll
                for (int j = 0; j < 8; ++j) {
                    const int k = kk * 32 + krow * 8 + j;
                    const float v = WH[g * 64 + k] * gs[q];
                    const _Float16 hi = (_Float16)v;
                    wh_h[q][kk][j] = hi;
                    wh_l[q][kk][j] = (_Float16)(v - (float)hi);
                }
            }
            bias[q] = (BI[g] + BH[g]) * gs[q];
        }
    }
    const float fcwv = fcw[wg * 16 + l15];

    // ---- state ----
    floatx4 c = {0.f, 0.f, 0.f, 0.f};
    half8 in0h, in1h;                 // input operand (grp0: x; grp1: h0)
    half8 hr0h, hr1h;                 // recurrent operand (grp0: h0; grp1: h1)
    #pragma unroll
    for (int j = 0; j < 8; ++j) {
        in0h[j] = (_Float16)0.f; in1h[j] = (_Float16)0.f;
        hr0h[j] = (_Float16)0.f; hr1h[j] = (_Float16)0.f;
    }
    floatx4 acc[4];
    #pragma unroll
    for (int q = 0; q < 4; ++q) acc[q] = (floatx4){0.f, 0.f, 0.f, 0.f};

    // x stream (grp0 only): A row l15 -> batch b0 + (l15 & 7)
    const float* xrow = x + (size_t)(b0 + (l15 & 7)) * (NSTEPS * IN_F);
    float xf[8], xfn[8];
    if (!grp) {
        #pragma unroll
        for (int j = 0; j < 8; ++j) {
            const int k = krow * 8 + j;
            xf[j] = (k < IN_F) ? xrow[k] : 0.f;   // t = 0
        }
    }

    float hv[4] = {0.f, 0.f, 0.f, 0.f};

    __syncthreads();   // LDS zero-init visible to all (full drain once, harmless)

    for (int i = 0; i <= NSTEPS + 1; ++i) {
        // ================= half 1 =================
        if (!grp) {
            if (i < NSTEPS) {
                // read h0(i-1) A-frags (written by grp0 in half2(i-1), cross-wave)
                const _Float16* sh = &h0buf[(i + 1) & 1][0];
                hr0h = *(const half8*)&sh[l15 * HSTRIDE + krow * 8];
                hr1h = *(const half8*)&sh[l15 * HSTRIDE + 32 + krow * 8];
                // cast x(i) to f16 fragment (in-register; covers ds_read latency)
                #pragma unroll
                for (int j = 0; j < 8; ++j) in0h[j] = (_Float16)xf[j];
                __builtin_amdgcn_s_setprio(1);
                // pass 1: x-side MFMAs (no LDS dependency)
                #pragma unroll
                for (int q = 0; q < 4; ++q) {
                    floatx4 a = {bias[q], bias[q], bias[q], bias[q]};
                    MFMA2(a, in0h, wi_h[q][0], wi_l[q][0]);
                    acc[q] = a;
                }
                // pass 2: recurrent MFMAs (hr reads have had ~160 cyc to land)
                #pragma unroll
                for (int q = 0; q < 4; ++q) {
                    MFMA2(acc[q], hr0h, wh_h[q][0], wh_l[q][0]);
                    MFMA2(acc[q], hr1h, wh_h[q][1], wh_l[q][1]);
                }
                __builtin_amdgcn_s_setprio(0);
                // prefetch x(i+1): stays in flight across raw barriers
                const int tn = (i + 1 < NSTEPS) ? (i + 1) : i;
                #pragma unroll
                for (int j = 0; j < 8; ++j) {
                    const int k = krow * 8 + j;
                    xfn[j] = (k < IN_F) ? xrow[(size_t)tn * IN_F + k] : 0.f;
                }
            }
        } else {
            if (i >= 1 && i <= NSTEPS) {
                // early-issue h0(i-1) frag reads (stable all of iter i; grp0
                // writes the OTHER h0 buffer in half2(i)); ACT covers latency
                const _Float16* sh0 = &h0buf[(i + 1) & 1][0];
                in0h = *(const half8*)&sh0[l15 * HSTRIDE + krow * 8];
                in1h = *(const half8*)&sh0[l15 * HSTRIDE + 32 + krow * 8];
            }
            if (i >= 2) {
                // ACT(i-2) from acc (computed half2(i-1)); write h1(i-2)
                #pragma unroll
                for (int r = 0; r < 4; ++r) {
                    const float iv = fast_rcp(1.f + EXP2(-acc[0][r]));
                    const float fv = fast_rcp(1.f + EXP2(-acc[1][r]));
                    const float gv = 2.f * fast_rcp(1.f + EXP2(-acc[2][r])) - 1.f;
                    const float ov = fast_rcp(1.f + EXP2(-acc[3][r]));
                    const float cn = fv * c[r] + iv * gv;
                    c[r] = cn;
                    hv[r] = ov * (2.f * fast_rcp(1.f + EXP2(NEG2LOG2E * cn)) - 1.f);
                }
                #pragma unroll
                for (int r = 0; r < 4; ++r) {
                    const int idx = (krow * 4 + r) * HSTRIDE + wg * 16 + l15;
                    h1buf[idx] = (_Float16)hv[r];
                }
            }
        }

        block_sync_lds();   // bar A (lgkm drain only)

        // ================= half 2 =================
        if (!grp) {
            if (i < NSTEPS) {
                // ACT(i); write h0(i)
                float h0v[4];
                #pragma unroll
                for (int r = 0; r < 4; ++r) {
                    const float iv = fast_rcp(1.f + EXP2(-acc[0][r]));
                    const float fv = fast_rcp(1.f + EXP2(-acc[1][r]));
                    const float gv = 2.f * fast_rcp(1.f + EXP2(-acc[2][r])) - 1.f;
                    const float ov = fast_rcp(1.f + EXP2(-acc[3][r]));
                    const float cn = fv * c[r] + iv * gv;
                    c[r] = cn;
                    h0v[r] = ov * (2.f * fast_rcp(1.f + EXP2(NEG2LOG2E * cn)) - 1.f);
                }
                _Float16* dst = &h0buf[i & 1][0];
                #pragma unroll
                for (int r = 0; r < 4; ++r) {
                    const int idx = (krow * 4 + r) * HSTRIDE + wg * 16 + l15;
                    dst[idx] = (_Float16)h0v[r];
                }
                #pragma unroll
                for (int j = 0; j < 8; ++j) xf[j] = xfn[j];
            }
        } else {
            if (i >= 1 && i <= NSTEPS) {
                // h1(i-2) frag reads (written half1(i) by grp1, across barA)
                hr0h = *(const half8*)&h1buf[l15 * HSTRIDE + krow * 8];
                hr1h = *(const half8*)&h1buf[l15 * HSTRIDE + 32 + krow * 8];
                __builtin_amdgcn_s_setprio(1);
                // pass 1: h0-input MFMAs (operands in registers since half1)
                #pragma unroll
                for (int q = 0; q < 4; ++q) {
                    floatx4 a = {bias[q], bias[q], bias[q], bias[q]};
                    MFMA2(a, in0h, wi_h[q][0], wi_l[q][0]);
                    MFMA2(a, in1h, wi_h[q][1], wi_l[q][1]);
                    acc[q] = a;
                }
                // pass 2: recurrent MFMAs (hr reads hidden under pass 1, ~310 cyc)
                #pragma unroll
                for (int q = 0; q < 4; ++q) {
                    MFMA2(acc[q], hr0h, wh_h[q][0], wh_l[q][0]);
                    MFMA2(acc[q], hr1h, wh_h[q][1], wh_l[q][1]);
                }
                __builtin_amdgcn_s_setprio(0);
            }
        }

        block_sync_lds();   // bar B (lgkm drain only)
    }

    // ---- FC on last h1 (grp1 hv = h1(NSTEPS-1) from its final ACT) ----
    if (grp) {
        float p[4];
        #pragma unroll
        for (int r = 0; r < 4; ++r) p[r] = hv[r] * fcwv;
        #pragma unroll
        for (int off = 1; off < 16; off <<= 1) {
            #pragma unroll
            for (int r = 0; r < 4; ++r)
                p[r] += __shfl_xor(p[r], off, 64);
        }
        if (l15 == 0) {
            #pragma unroll
            for (int r = 0; r < 4; ++r)
                red[wg][krow * 4 + r] = p[r];
        }
    }
    __syncthreads();
    if (tid < 8) {
        float v = fcb[0];
        v += red[0][tid] + red[1][tid] + red[2][tid] + red[3][tid];
        out[b0 + tid] = v;
    }
}

extern "C" void kernel_launch(void* const* d_in, const int* in_sizes, int n_in,
                              void* d_out, int out_size, void* d_ws, size_t ws_size,
                              hipStream_t stream) {
    (void)n_in; (void)d_ws; (void)ws_size; (void)out_size;
    const float* xp    = (const float*)d_in[0];
    const float* Wih0  = (const float*)d_in[1];
    const float* Whh0  = (const float*)d_in[2];
    const float* bih0  = (const float*)d_in[3];
    const float* bhh0  = (const float*)d_in[4];
    const float* Wih1  = (const float*)d_in[5];
    const float* Whh1  = (const float*)d_in[6];
    const float* bih1  = (const float*)d_in[7];
    const float* bhh1  = (const float*)d_in[8];
    const float* fcw   = (const float*)d_in[9];
    const float* fcb   = (const float*)d_in[10];
    float* outp        = (float*)d_out;

    const int B = in_sizes[0] / (NSTEPS * IN_F);   // 2048
    const int nblocks = B / 8;                     // 256
    hipLaunchKernelGGL(lstm2_fused, dim3(nblocks), dim3(512), 0, stream,
                       xp, Wih0, Whh0, bih0, bhh0, Wih1, Whh1, bih1, bhh1,
                       fcw, fcb, outp);
}